// Round 21
// baseline (549.486 us; speedup 1.0000x reference)
//
#include <hip/hip_runtime.h>

#define N_ANCH 8732
#define NCLS   21
#define BATCH  128
#define TOPK   200
#define CONF_T 0.01f
#define NMS_T  0.45f
#define HSIZE  1024        // 64 lanes x 16 buckets; populated range [0, 861]
#define CAND_MAX 1024

// XLA:CPU GenerateVF32Exp (classic Cephes) compiled with AllowFPOpFusion=Fast.
__device__ __forceinline__ float exp_np(float x) {
    const float fx = floorf(__fmaf_rn(x, 1.442695040888963f, 0.5f));
    float t = __fmaf_rn(fx, -0.693359375f, x);
    t = __fmaf_rn(fx, 2.12194440e-4f, t);
    const float z = __fmul_rn(t, t);
    float y = 1.9875691500e-4f;
    y = __fmaf_rn(y, t, 1.3981999507e-3f);
    y = __fmaf_rn(y, t, 8.3334519073e-3f);
    y = __fmaf_rn(y, t, 4.1665795894e-2f);
    y = __fmaf_rn(y, t, 1.6666665459e-1f);
    y = __fmaf_rn(y, t, 5.0000001201e-1f);
    y = __fmaf_rn(y, z, t);
    y = __fadd_rn(y, 1.0f);
    return ldexpf(y, (int)fx);
}

// ---------------------------------------------------------------------------
// Kernel A (verified r18): VF=16 masked-tail vectorized reduce softmax +
// FMA-fused decode. probs transposed [b][c-1][n]; boxes [b][n][4].
// ---------------------------------------------------------------------------
__global__ __launch_bounds__(256) void prep_kernel(
    const float* __restrict__ loc, const float* __restrict__ conf,
    const float* __restrict__ dbox, float* __restrict__ probs,
    float* __restrict__ boxes)
{
    __shared__ float srow[256 * NCLS];
    const int block_row0 = blockIdx.x * 256;
    const float* cbase = conf + (size_t)block_row0 * NCLS;
    for (int i = threadIdx.x; i < 256 * NCLS; i += 256) srow[i] = cbase[i];
    __syncthreads();

    const int row = block_row0 + threadIdx.x;      // grid exact: 4366*256
    const int b = row / N_ANCH;
    const int n = row - b * N_ANCH;

    float e[NCLS];
    float m = srow[threadIdx.x * NCLS];
#pragma unroll
    for (int c = 1; c < NCLS; ++c) m = fmaxf(m, srow[threadIdx.x * NCLS + c]);
#pragma unroll
    for (int c = 0; c < NCLS; ++c)
        e[c] = exp_np(__fsub_rn(srow[threadIdx.x * NCLS + c], m));

    // VF=16 masked-tail reduce (verified r18)
    float acc[16];
#pragma unroll
    for (int j = 0; j < 16; ++j) acc[j] = e[j];
#pragma unroll
    for (int j = 0; j < 5; ++j) acc[j] = __fadd_rn(acc[j], e[16 + j]);
    float u[8];
#pragma unroll
    for (int j = 0; j < 8; ++j) u[j] = __fadd_rn(acc[j], acc[j + 8]);
    const float v0 = __fadd_rn(u[0], u[4]), v1 = __fadd_rn(u[1], u[5]);
    const float v2 = __fadd_rn(u[2], u[6]), v3 = __fadd_rn(u[3], u[7]);
    const float w0 = __fadd_rn(v0, v2), w1 = __fadd_rn(v1, v3);
    const float s  = __fadd_rn(w0, w1);

#pragma unroll
    for (int c = 1; c < NCLS; ++c)
        probs[((size_t)b * 20 + (c - 1)) * N_ANCH + n] = __fdiv_rn(e[c], s);

    const float4 l = *(const float4*)(loc + (size_t)row * 4);
    const float4 d = *(const float4*)(dbox + (size_t)n * 4);
    const float cx = __fmaf_rn(__fmul_rn(l.x, 0.1f), d.z, d.x);
    const float cy = __fmaf_rn(__fmul_rn(l.y, 0.1f), d.w, d.y);
    const float w  = __fmul_rn(d.z, exp_np(__fmul_rn(l.z, 0.2f)));
    const float h  = __fmul_rn(d.w, exp_np(__fmul_rn(l.w, 0.2f)));
    const float x1 = __fmaf_rn(w, -0.5f, cx);
    const float y1 = __fmaf_rn(h, -0.5f, cy);
    float4 o; o.x = x1; o.y = y1; o.z = __fadd_rn(x1, w); o.w = __fadd_rn(y1, h);
    *(float4*)(boxes + (size_t)row * 4) = o;
}

// ---------------------------------------------------------------------------
// Kernel B v3: SINGLE-WAVE workgroup (64 threads) — all ~230 __syncthreads
// become near-free one-wave barriers. Same verified selection semantics
// (histogram top-200, value desc / index ASC ties) and verified NMS.
// ---------------------------------------------------------------------------
__global__ __launch_bounds__(64) void nms_kernel(
    const float* __restrict__ probs, const float* __restrict__ boxes,
    float* __restrict__ out)
{
    const int task = blockIdx.x;                  // b*21 + c
    const int b = task / NCLS;
    const int c = task - b * NCLS;
    float* obase = out + (size_t)task * (TOPK * 5);
    const int tid = threadIdx.x;

    if (c == 0) {
        for (int i = tid; i < TOPK * 5; i += 64) obase[i] = 0.f;
        return;
    }
    const float* prow = probs + ((size_t)b * 20 + (c - 1)) * N_ANCH;

    __shared__ int hist[HSIZE];
    __shared__ int scanbuf[64];
    __shared__ unsigned long long cand[CAND_MAX];
    __shared__ int selB;
    __shared__ int cnts[2];
    __shared__ unsigned ck[TOPK];
    __shared__ int  cn[TOPK];
    __shared__ unsigned sk[TOPK];
    __shared__ int  sn_[TOPK];
    __shared__ float bx1[TOPK], by1[TOPK], bx2[TOPK], by2[TOPK], bar[TOPK], bsc[TOPK];
    __shared__ int  keep[TOPK], pos_[TOPK];

    // ---- pass 1: histogram by top 16 bits ---------------------------------
    for (int i = tid; i < HSIZE; i += 64) hist[i] = 0;
    __syncthreads();
#pragma unroll 4
    for (int n = tid; n < N_ANCH; n += 64) {
        const float s = prow[n];
        if (s > CONF_T)
            atomicAdd(&hist[(int)((__float_as_uint(s) >> 16) - 0x3C23u)], 1);
    }
    __syncthreads();

    // ---- boundary bucket B: count(>B) < 200 <= count(>=B) -----------------
    const int hbase = HSIZE - 16 * (tid + 1);      // in [0, 1008]
    int part = 0;
#pragma unroll
    for (int j = 0; j < 16; ++j) part += hist[hbase + j];
    scanbuf[tid] = part;
    __syncthreads();
    for (int off = 1; off < 64; off <<= 1) {
        const int v = (tid >= off) ? scanbuf[tid - off] : 0;
        __syncthreads();
        scanbuf[tid] += v;
        __syncthreads();
    }
    const int excl  = scanbuf[tid] - part;         // keys in buckets above mine
    const int total = scanbuf[63];
    if (tid == 0 && total < TOPK) selB = -1;       // all valid keys selected
    if (excl < TOPK && excl + part >= TOPK) {      // exactly one crossing lane
        int cacc = excl;
        for (int j = 15; j >= 0; --j) {            // hbase+15 is highest bucket
            const int h = hist[hbase + j];
            if (cacc + h >= TOPK) { selB = hbase + j; break; }
            cacc += h;
        }
    }
    if (tid == 0) { cnts[0] = 0; cnts[1] = 0; }
    __syncthreads();
    const int B = selB;

    // ---- pass 2: compact definites (>B); collect bucket-B candidates ------
#pragma unroll 4
    for (int n = tid; n < N_ANCH; n += 64) {
        const float s = prow[n];
        if (s > CONF_T) {
            const unsigned kk = __float_as_uint(s);
            const int bkt = (int)((kk >> 16) - 0x3C23u);
            if (bkt > B) {
                const int p = atomicAdd(&cnts[0], 1);
                ck[p] = kk; cn[p] = n;
            } else if (bkt == B) {
                const int q = atomicAdd(&cnts[1], 1);
                if (q < CAND_MAX)
                    cand[q] = ((unsigned long long)kk << 32) | (unsigned)(~n);
            }
        }
    }
    __syncthreads();
    const int ndef  = cnts[0];                     // < 200 by construction
    const int slots = TOPK - ndef;
    int cc = cnts[1]; if (cc > CAND_MAX) cc = CAND_MAX;
    // exact rank-select among candidates: (value desc, index asc) packed key
    for (int i = tid; i < cc; i += 64) {
        const unsigned long long mine = cand[i];
        int rank = 0;
        for (int j = 0; j < cc; ++j) rank += (cand[j] > mine) ? 1 : 0;
        if (rank < slots) {
            const int p = atomicAdd(&cnts[0], 1);
            ck[p] = (unsigned)(mine >> 32);
            cn[p] = (int)(~(unsigned)mine);
        }
    }
    __syncthreads();
    const int cnt_arr = cnts[0];                  // <= 200

    // ---- rank-sort: (value desc, index ASC among equals) — verified -------
    for (int i = tid; i < TOPK; i += 64) { sk[i] = 0u; sn_[i] = -1; }
    __syncthreads();
    for (int i = tid; i < cnt_arr; i += 64) {
        const unsigned mk = ck[i];
        const int mn = cn[i];
        int rank = 0;
        for (int j = 0; j < cnt_arr; ++j) {
            const unsigned kj = ck[j];
            rank += (kj > mk || (kj == mk && cn[j] < mn)) ? 1 : 0;
        }
        sk[rank] = mk; sn_[rank] = mn;
    }
    __syncthreads();

    // ---- gather boxes (f32), init keep — verified -------------------------
    for (int i = tid; i < TOPK; i += 64) {
        const int n = sn_[i];
        float sc = 0.f;
        float4 bx = make_float4(0.f, 0.f, 0.f, 0.f);
        if (n >= 0) {
            sc = __uint_as_float(sk[i]);
            bx = *(const float4*)(boxes + ((size_t)b * N_ANCH + n) * 4);
        }
        bsc[i] = sc;
        bx1[i] = bx.x; by1[i] = bx.y; bx2[i] = bx.z; by2[i] = bx.w;
        bar[i] = __fmul_rn(__fsub_rn(bx.z, bx.x), __fsub_rn(bx.w, bx.y));
        keep[i] = (sc > CONF_T) ? 1 : 0;
    }
    __syncthreads();

    // ---- sequential NMS, exact f32 op order — verified semantics ----------
    for (int i = 0; i < TOPK; ++i) {
        const int ki = keep[i];
        const float ix1 = bx1[i], iy1 = by1[i], ix2 = bx2[i], iy2 = by2[i], ia = bar[i];
#pragma unroll
        for (int s4 = 0; s4 < 4; ++s4) {
            const int j = tid + 64 * s4;
            if (j < TOPK && j > i && ki && keep[j]) {
                const float w = fmaxf(0.f, __fsub_rn(fminf(bx2[j], ix2), fmaxf(bx1[j], ix1)));
                const float h = fmaxf(0.f, __fsub_rn(fminf(by2[j], iy2), fmaxf(by1[j], iy1)));
                const float inter = __fmul_rn(w, h);
                const float denom = __fadd_rn(__fsub_rn(bar[j], inter), ia);
                const float iou = __fdiv_rn(inter, denom);
                if (iou > NMS_T) keep[j] = 0;
            }
        }
        __syncthreads();
    }

    // ---- stable compaction + zero fill (direct to global) -----------------
    if (tid == 0) {
        int ccnt = 0;
        for (int rr = 0; rr < TOPK; ++rr) { pos_[rr] = ccnt; ccnt += keep[rr]; }
    }
    __syncthreads();
    for (int i = tid; i < TOPK * 5; i += 64) obase[i] = 0.f;
    __syncthreads();                               // drain zeros before scatter
    for (int i = tid; i < TOPK; i += 64) {
        if (keep[i]) {
            const int d = pos_[i];
            obase[d * 5 + 0] = bsc[i];
            obase[d * 5 + 1] = bx1[i];
            obase[d * 5 + 2] = by1[i];
            obase[d * 5 + 3] = bx2[i];
            obase[d * 5 + 4] = by2[i];
        }
    }
}

extern "C" void kernel_launch(void* const* d_in, const int* in_sizes, int n_in,
                              void* d_out, int out_size, void* d_ws, size_t ws_size,
                              hipStream_t stream) {
    (void)in_sizes; (void)n_in; (void)out_size; (void)ws_size;
    const float* loc  = (const float*)d_in[0];
    const float* conf = (const float*)d_in[1];
    const float* dbox = (const float*)d_in[2];
    float* out   = (float*)d_out;
    float* probs = (float*)d_ws;                                            // 89,415,680 B
    float* boxes = (float*)((char*)d_ws + (size_t)BATCH * 20 * N_ANCH * 4); // +17,883,136 B

    prep_kernel<<<(BATCH * N_ANCH) / 256, 256, 0, stream>>>(loc, conf, dbox, probs, boxes);
    nms_kernel<<<BATCH * NCLS, 64, 0, stream>>>(probs, boxes, out);
}

// Round 22
// 197.166 us; speedup vs baseline: 2.7869x; 2.7869x over previous
//
#include <hip/hip_runtime.h>

#define N_ANCH 8732
#define NCLS   21
#define BATCH  128
#define TOPK   200
#define CONF_T 0.01f
#define NMS_T  0.45f
#define HSIZE  1024        // 256 threads x 4 buckets; populated range [0, 861]
#define CAND_MAX 1024
#define NQ4    2183        // 8732 / 4 exactly

// XLA:CPU GenerateVF32Exp (classic Cephes) compiled with AllowFPOpFusion=Fast.
__device__ __forceinline__ float exp_np(float x) {
    const float fx = floorf(__fmaf_rn(x, 1.442695040888963f, 0.5f));
    float t = __fmaf_rn(fx, -0.693359375f, x);
    t = __fmaf_rn(fx, 2.12194440e-4f, t);
    const float z = __fmul_rn(t, t);
    float y = 1.9875691500e-4f;
    y = __fmaf_rn(y, t, 1.3981999507e-3f);
    y = __fmaf_rn(y, t, 8.3334519073e-3f);
    y = __fmaf_rn(y, t, 4.1665795894e-2f);
    y = __fmaf_rn(y, t, 1.6666665459e-1f);
    y = __fmaf_rn(y, t, 5.0000001201e-1f);
    y = __fmaf_rn(y, z, t);
    y = __fadd_rn(y, 1.0f);
    return ldexpf(y, (int)fx);
}

// ---------------------------------------------------------------------------
// Kernel A (verified r18): VF=16 masked-tail vectorized reduce softmax +
// FMA-fused decode. probs transposed [b][c-1][n]; boxes [b][n][4].
// ---------------------------------------------------------------------------
__global__ __launch_bounds__(256) void prep_kernel(
    const float* __restrict__ loc, const float* __restrict__ conf,
    const float* __restrict__ dbox, float* __restrict__ probs,
    float* __restrict__ boxes)
{
    __shared__ float srow[256 * NCLS];
    const int block_row0 = blockIdx.x * 256;
    const float* cbase = conf + (size_t)block_row0 * NCLS;
    for (int i = threadIdx.x; i < 256 * NCLS; i += 256) srow[i] = cbase[i];
    __syncthreads();

    const int row = block_row0 + threadIdx.x;      // grid exact: 4366*256
    const int b = row / N_ANCH;
    const int n = row - b * N_ANCH;

    float e[NCLS];
    float m = srow[threadIdx.x * NCLS];
#pragma unroll
    for (int c = 1; c < NCLS; ++c) m = fmaxf(m, srow[threadIdx.x * NCLS + c]);
#pragma unroll
    for (int c = 0; c < NCLS; ++c)
        e[c] = exp_np(__fsub_rn(srow[threadIdx.x * NCLS + c], m));

    // VF=16 masked-tail reduce (verified r18)
    float acc[16];
#pragma unroll
    for (int j = 0; j < 16; ++j) acc[j] = e[j];
#pragma unroll
    for (int j = 0; j < 5; ++j) acc[j] = __fadd_rn(acc[j], e[16 + j]);
    float u[8];
#pragma unroll
    for (int j = 0; j < 8; ++j) u[j] = __fadd_rn(acc[j], acc[j + 8]);
    const float v0 = __fadd_rn(u[0], u[4]), v1 = __fadd_rn(u[1], u[5]);
    const float v2 = __fadd_rn(u[2], u[6]), v3 = __fadd_rn(u[3], u[7]);
    const float w0 = __fadd_rn(v0, v2), w1 = __fadd_rn(v1, v3);
    const float s  = __fadd_rn(w0, w1);

#pragma unroll
    for (int c = 1; c < NCLS; ++c)
        probs[((size_t)b * 20 + (c - 1)) * N_ANCH + n] = __fdiv_rn(e[c], s);

    const float4 l = *(const float4*)(loc + (size_t)row * 4);
    const float4 d = *(const float4*)(dbox + (size_t)n * 4);
    const float cx = __fmaf_rn(__fmul_rn(l.x, 0.1f), d.z, d.x);
    const float cy = __fmaf_rn(__fmul_rn(l.y, 0.1f), d.w, d.y);
    const float w  = __fmul_rn(d.z, exp_np(__fmul_rn(l.z, 0.2f)));
    const float h  = __fmul_rn(d.w, exp_np(__fmul_rn(l.w, 0.2f)));
    const float x1 = __fmaf_rn(w, -0.5f, cx);
    const float y1 = __fmaf_rn(h, -0.5f, cy);
    float4 o; o.x = x1; o.y = y1; o.z = __fadd_rn(x1, w); o.w = __fadd_rn(y1, h);
    *(float4*)(boxes + (size_t)row * 4) = o;
}

// ---------------------------------------------------------------------------
// Kernel B (selection only): verified histogram top-200 + rank-sort
// (value desc, index ASC ties). Writes ordered (score, x1,y1,x2,y2) x200
// back into the task's own prob row (reads complete before writes).
// ---------------------------------------------------------------------------
__global__ __launch_bounds__(256) void sel_kernel(
    const float* __restrict__ probs, const float* __restrict__ boxes,
    float* __restrict__ probs_mut)
{
    const int task = blockIdx.x;                  // b*21 + c
    const int b = task / NCLS;
    const int c = task - b * NCLS;
    const int tid = threadIdx.x;
    if (c == 0) return;                           // class 0 handled in nms_kernel

    const float* prow = probs + ((size_t)b * 20 + (c - 1)) * N_ANCH;

    __shared__ int hist[HSIZE];
    __shared__ int scanbuf[256];
    __shared__ unsigned long long cand[CAND_MAX];
    __shared__ int selB;
    __shared__ int cnts[2];
    __shared__ unsigned ck[TOPK];
    __shared__ int  cn[TOPK];
    __shared__ unsigned sk[TOPK];
    __shared__ int  sn_[TOPK];

    // ---- pass 1: histogram by top 16 bits (float4 loads) ------------------
    for (int i = tid; i < HSIZE; i += 256) hist[i] = 0;
    __syncthreads();
    for (int idx = tid; idx < NQ4; idx += 256) {
        const float4 v = *(const float4*)(prow + idx * 4);
        if (v.x > CONF_T) atomicAdd(&hist[(int)((__float_as_uint(v.x) >> 16) - 0x3C23u)], 1);
        if (v.y > CONF_T) atomicAdd(&hist[(int)((__float_as_uint(v.y) >> 16) - 0x3C23u)], 1);
        if (v.z > CONF_T) atomicAdd(&hist[(int)((__float_as_uint(v.z) >> 16) - 0x3C23u)], 1);
        if (v.w > CONF_T) atomicAdd(&hist[(int)((__float_as_uint(v.w) >> 16) - 0x3C23u)], 1);
    }
    __syncthreads();

    // ---- boundary bucket B: count(>B) < 200 <= count(>=B) -----------------
    const int hbase = HSIZE - 4 * (tid + 1);       // in [0, 1020]
    const int part = hist[hbase] + hist[hbase + 1] + hist[hbase + 2] + hist[hbase + 3];
    scanbuf[tid] = part;
    __syncthreads();
    for (int off = 1; off < 256; off <<= 1) {
        const int v = (tid >= off) ? scanbuf[tid - off] : 0;
        __syncthreads();
        scanbuf[tid] += v;
        __syncthreads();
    }
    const int excl  = scanbuf[tid] - part;
    const int total = scanbuf[255];
    if (tid == 0 && total < TOPK) selB = -1;
    if (excl < TOPK && excl + part >= TOPK) {
        int cacc = excl;
        for (int j = 3; j >= 0; --j) {
            const int h = hist[hbase + j];
            if (cacc + h >= TOPK) { selB = hbase + j; break; }
            cacc += h;
        }
    }
    if (tid == 0) { cnts[0] = 0; cnts[1] = 0; }
    __syncthreads();
    const int B = selB;

    // ---- pass 2: compact definites (>B); collect bucket-B candidates ------
    for (int idx = tid; idx < NQ4; idx += 256) {
        const float4 v = *(const float4*)(prow + idx * 4);
        const float vv[4] = {v.x, v.y, v.z, v.w};
#pragma unroll
        for (int q = 0; q < 4; ++q) {
            const float s = vv[q];
            if (s > CONF_T) {
                const unsigned kk = __float_as_uint(s);
                const int bkt = (int)((kk >> 16) - 0x3C23u);
                if (bkt > B) {
                    const int p = atomicAdd(&cnts[0], 1);
                    ck[p] = kk; cn[p] = idx * 4 + q;
                } else if (bkt == B) {
                    const int qq = atomicAdd(&cnts[1], 1);
                    if (qq < CAND_MAX)
                        cand[qq] = ((unsigned long long)kk << 32) | (unsigned)(~(idx * 4 + q));
                }
            }
        }
    }
    __syncthreads();
    const int ndef  = cnts[0];                     // < 200 by construction
    const int slots = TOPK - ndef;
    int cc = cnts[1]; if (cc > CAND_MAX) cc = CAND_MAX;
    for (int i = tid; i < cc; i += 256) {
        const unsigned long long mine = cand[i];
        int rank = 0;
        for (int j = 0; j < cc; ++j) rank += (cand[j] > mine) ? 1 : 0;
        if (rank < slots) {
            const int p = atomicAdd(&cnts[0], 1);
            ck[p] = (unsigned)(mine >> 32);
            cn[p] = (int)(~(unsigned)mine);
        }
    }
    __syncthreads();
    const int cnt_arr = cnts[0];                  // <= 200

    // ---- rank-sort: (value desc, index ASC among equals) — verified -------
    if (tid < TOPK) { sk[tid] = 0u; sn_[tid] = -1; }
    __syncthreads();
    if (tid < cnt_arr) {
        const unsigned mk = ck[tid];
        const int mn = cn[tid];
        int rank = 0;
        for (int j = 0; j < cnt_arr; ++j) {
            const unsigned kj = ck[j];
            rank += (kj > mk || (kj == mk && cn[j] < mn)) ? 1 : 0;
        }
        sk[rank] = mk; sn_[rank] = mn;
    }
    __syncthreads();

    // ---- gather boxes, write ordered selection into own prob row ----------
    float* selrow = probs_mut + ((size_t)b * 20 + (c - 1)) * N_ANCH;
    for (int i = tid; i < TOPK; i += 256) {
        const int n = sn_[i];
        float scv = 0.f;
        float4 bx = make_float4(0.f, 0.f, 0.f, 0.f);
        if (n >= 0) {
            scv = __uint_as_float(sk[i]);
            bx = *(const float4*)(boxes + ((size_t)b * N_ANCH + n) * 4);
        }
        float* dst = selrow + i * 5;
        dst[0] = scv; dst[1] = bx.x; dst[2] = bx.y; dst[3] = bx.z; dst[4] = bx.w;
    }
}

// ---------------------------------------------------------------------------
// Kernel C: NMS + stable compaction, ONE WAVE PER TASK (4 tasks/block).
// Boxes in registers (4 slots/lane); sequential-i loop is wave-synchronous
// via __shfl broadcast — zero barriers. Identical FP ops / order semantics.
// ---------------------------------------------------------------------------
__global__ __launch_bounds__(256) void nms_kernel(
    const float* __restrict__ sel, float* __restrict__ out)
{
    const int wv = threadIdx.x >> 6;              // 0..3
    const int lane = threadIdx.x & 63;
    const int task = blockIdx.x * 4 + wv;         // grid 672*4 = 2688 exact
    const int b = task / NCLS;
    const int c = task - b * NCLS;
    float* obase = out + (size_t)task * (TOPK * 5);
    __shared__ float outrow[4][TOPK * 5];

    if (c == 0) {
        for (int i = lane; i < TOPK * 5; i += 64) obase[i] = 0.f;
        return;
    }
    const float* srow = sel + ((size_t)b * 20 + (c - 1)) * N_ANCH;

    float sc[4], x1[4], y1[4], x2[4], y2[4], ar[4];
    int kp[4];
#pragma unroll
    for (int s = 0; s < 4; ++s) {
        const int i = s * 64 + lane;
        float a = 0.f, p1 = 0.f, p2 = 0.f, p3 = 0.f, p4 = 0.f;
        if (i < TOPK) {
            a  = srow[i * 5 + 0];
            p1 = srow[i * 5 + 1]; p2 = srow[i * 5 + 2];
            p3 = srow[i * 5 + 3]; p4 = srow[i * 5 + 4];
        }
        sc[s] = a; x1[s] = p1; y1[s] = p2; x2[s] = p3; y2[s] = p4;
        ar[s] = __fmul_rn(__fsub_rn(p3, p1), __fsub_rn(p4, p2));  // verified area op
        kp[s] = (a > CONF_T) ? 1 : 0;
    }

    // ---- sequential NMS, wave-synchronous (no barriers) -------------------
#pragma unroll
    for (int si = 0; si < 4; ++si) {
        const int ilim = (si < 3) ? 64 : (TOPK - 192);
        for (int o = 0; o < ilim; ++o) {
            const int i = si * 64 + o;
            const int ki = __shfl(kp[si], o);
            if (!ki) continue;                     // uniform branch
            const float ix1 = __shfl(x1[si], o);
            const float iy1 = __shfl(y1[si], o);
            const float ix2 = __shfl(x2[si], o);
            const float iy2 = __shfl(y2[si], o);
            const float ia  = __shfl(ar[si], o);
#pragma unroll
            for (int s = 0; s < 4; ++s) {
                const int j = s * 64 + lane;
                if (j > i && j < TOPK && kp[s]) {
                    const float w = fmaxf(0.f, __fsub_rn(fminf(x2[s], ix2), fmaxf(x1[s], ix1)));
                    const float h = fmaxf(0.f, __fsub_rn(fminf(y2[s], iy2), fmaxf(y1[s], iy1)));
                    const float inter = __fmul_rn(w, h);
                    const float denom = __fadd_rn(__fsub_rn(ar[s], inter), ia);
                    const float iou = __fdiv_rn(inter, denom);
                    if (iou > NMS_T) kp[s] = 0;
                }
            }
        }
    }

    // ---- stable compaction via ballot prefix ------------------------------
    unsigned long long msk[4];
#pragma unroll
    for (int s = 0; s < 4; ++s) msk[s] = __ballot(kp[s] != 0);
    const unsigned long long lt = (1ull << lane) - 1ull;

    for (int i = lane; i < TOPK * 5; i += 64) outrow[wv][i] = 0.f;
    int base = 0;
#pragma unroll
    for (int s = 0; s < 4; ++s) {
        if (kp[s]) {
            const int d = base + (int)__popcll(msk[s] & lt);
            outrow[wv][d * 5 + 0] = sc[s];
            outrow[wv][d * 5 + 1] = x1[s];
            outrow[wv][d * 5 + 2] = y1[s];
            outrow[wv][d * 5 + 3] = x2[s];
            outrow[wv][d * 5 + 4] = y2[s];
        }
        base += (int)__popcll(msk[s]);
    }
    for (int i = lane; i < TOPK * 5; i += 64) obase[i] = outrow[wv][i];
}

extern "C" void kernel_launch(void* const* d_in, const int* in_sizes, int n_in,
                              void* d_out, int out_size, void* d_ws, size_t ws_size,
                              hipStream_t stream) {
    (void)in_sizes; (void)n_in; (void)out_size; (void)ws_size;
    const float* loc  = (const float*)d_in[0];
    const float* conf = (const float*)d_in[1];
    const float* dbox = (const float*)d_in[2];
    float* out   = (float*)d_out;
    float* probs = (float*)d_ws;                                            // 89,415,680 B
    float* boxes = (float*)((char*)d_ws + (size_t)BATCH * 20 * N_ANCH * 4); // +17,883,136 B

    prep_kernel<<<(BATCH * N_ANCH) / 256, 256, 0, stream>>>(loc, conf, dbox, probs, boxes);
    sel_kernel<<<BATCH * NCLS, 256, 0, stream>>>(probs, boxes, probs);
    nms_kernel<<<(BATCH * NCLS) / 4, 256, 0, stream>>>(probs, out);
}